// Round 7
// baseline (738.574 us; speedup 1.0000x reference)
//
#include <hip/hip_runtime.h>
#include <hip/hip_bf16.h>
#include <math.h>

typedef __hip_bfloat16 bf16;

#define B_    4
#define C_    180
#define ROWS_ 65536   // B*H*W
#define NH_   6
#define HD_   30
#define NT_   256     // tokens per window
#define CC_   60      // conv mid channels
#define HID_  720
#define ATT_SCALE 0.18257418583505536f  // 30^-0.5

typedef short  short4v __attribute__((ext_vector_type(4)));
typedef short  short8v __attribute__((ext_vector_type(8)));
typedef __bf16 bf16x8  __attribute__((ext_vector_type(8)));
typedef float  f32x4   __attribute__((ext_vector_type(4)));

__device__ __forceinline__ float b2f(bf16 v){ return __bfloat162float(v); }
__device__ __forceinline__ bf16  f2b(float v){ return __float2bfloat16(v); }
__device__ __forceinline__ float ldf(const bf16* p){ return __bfloat162float(*p); }
__device__ __forceinline__ float ldf(const float* p){ return *p; }
__device__ __forceinline__ float gelu_f(float v){
    return 0.5f * v * (1.0f + erff(v * 0.70710678118654752440f));
}
__device__ __forceinline__ f32x4 mfma16(short8v a, short8v b, f32x4 c){
    return __builtin_amdgcn_mfma_f32_16x16x32_bf16(
        __builtin_bit_cast(bf16x8, a), __builtin_bit_cast(bf16x8, b), c, 0, 0, 0);
}
__device__ __forceinline__ short8v cat44(short4v lo, short4v hi){
    return short8v{lo[0],lo[1],lo[2],lo[3],hi[0],hi[1],hi[2],hi[3]};
}
__device__ __forceinline__ short8v ld8(const bf16* p){
    return cat44(*(const short4v*)p, *(const short4v*)(p + 4));
}

// window-ordered row r -> natural row
__device__ __forceinline__ int inv_win(int r){
    int b = r >> 14, w6 = (r >> 8) & 63, t = r & 255;
    int py = ((w6 >> 3) << 4) + (t >> 4);
    int px = ((w6 & 7) << 4) + (t & 15);
    return (b << 14) + (py << 7) + px;
}

// ---------------- LayerNorm: one wave per row of 180 ----------------
template<typename TIN>
__global__ __launch_bounds__(256) void ln_kernel(const TIN* __restrict__ xin,
        const float* __restrict__ gw, const float* __restrict__ gb,
        bf16* __restrict__ xn)
{
    int row  = blockIdx.x * 4 + (threadIdx.x >> 6);
    int lane = threadIdx.x & 63;
    const TIN* xp = xin + (size_t)row * C_;
    float v0 = ldf(xp + lane);
    float v1 = ldf(xp + lane + 64);
    float v2 = (lane < 52) ? ldf(xp + lane + 128) : 0.f;
    float s  = v0 + v1 + v2;
    float sq = v0*v0 + v1*v1 + v2*v2;
    for (int off = 32; off > 0; off >>= 1){
        s  += __shfl_xor(s,  off);
        sq += __shfl_xor(sq, off);
    }
    float mu  = s * (1.f / 180.f);
    float inv = rsqrtf(sq * (1.f / 180.f) - mu * mu + 1e-5f);
    size_t ro = (size_t)row * C_;
    #pragma unroll
    for (int e = 0; e < 3; e++){
        int c = lane + e * 64;
        if (c < C_){
            float v = (e == 0) ? v0 : (e == 1 ? v1 : v2);
            xn[ro + c] = f2b((v - mu) * inv * gw[c] + gb[c]);
        }
    }
}

// ---------------- weight transpose: W[K][N] -> BT[NP][KP] bf16, zero-padded ----
__global__ __launch_bounds__(256) void twt_kernel(const float* __restrict__ w,
        bf16* __restrict__ bt, int K, int N, int KP, int NP)
{
    int idx = blockIdx.x * 256 + threadIdx.x;
    if (idx >= NP * KP) return;
    int n = idx / KP, k = idx % KP;
    float v = (n < N && k < K) ? w[(size_t)k * N + n] : 0.f;
    bt[idx] = f2b(v);
}
// conv weight: w[((seg*CIN+ci))*N + n] -> BT[NP][9*SEGP]
__global__ __launch_bounds__(256) void twc_kernel(const float* __restrict__ w,
        bf16* __restrict__ bt, int CIN, int N, int SEGP, int NP)
{
    int KP = 9 * SEGP;
    int idx = blockIdx.x * 256 + threadIdx.x;
    if (idx >= NP * KP) return;
    int n = idx / KP, kk = idx % KP;
    int seg = kk / SEGP, ci = kk - seg * SEGP;
    float v = (n < N && ci < CIN) ? w[((size_t)seg * CIN + ci) * N + n] : 0.f;
    bt[idx] = f2b(v);
}

// ---------------- adaptive avg pool partials ----------------
__global__ __launch_bounds__(192) void pool_kernel(const bf16* __restrict__ y2,
                                                   float* __restrict__ pooled)
{
    int b = blockIdx.x >> 6;
    int chunk = blockIdx.x & 63;
    int c = threadIdx.x;
    if (c >= C_) return;
    const bf16* p = y2 + ((size_t)(b << 14) + (chunk << 8)) * C_ + c;
    float s = 0.f;
    for (int i = 0; i < 256; i++) s += b2f(p[(size_t)i * C_]);
    atomicAdd(&pooled[b * C_ + c], s);
}

// ---------------- channel attention tiny MLP ----------------
__global__ __launch_bounds__(192) void ca_kernel(const float* __restrict__ pooled,
        const float* __restrict__ w1, const float* __restrict__ b1,
        const float* __restrict__ w2, const float* __restrict__ b2v,
        float* __restrict__ aout)
{
    __shared__ float t[NH_];
    int b = blockIdx.x, tid = threadIdx.x;
    if (tid < 6){
        float s = b1[tid];
        for (int c = 0; c < C_; c++)
            s += pooled[b * C_ + c] * (1.f / 16384.f) * w1[c * 6 + tid];
        t[tid] = fmaxf(s, 0.f);
    }
    __syncthreads();
    if (tid < C_){
        float s = b2v[tid];
        #pragma unroll
        for (int j = 0; j < 6; j++) s += t[j] * w2[j * C_ + tid];
        aout[b * C_ + tid] = 1.f / (1.f + __expf(-s));
    }
}

// ---------------- relative position bias table (bf16) ----------------
__global__ __launch_bounds__(256) void rpb_kernel(const float* __restrict__ rpb,
        const int* __restrict__ rpi, bf16* __restrict__ biasT)
{
    int idx = blockIdx.x * 256 + threadIdx.x;     // h*65536 + i*256 + j
    int h = idx >> 16, ij = idx & 65535;
    biasT[idx] = f2b(rpb[rpi[ij] * 6 + h]);
}

// ================= unified MFMA GEMM: direct-fragment loads, NO LDS ============
// 128x64 tile, 4 waves; wave = 32x64 via 2x4 mfma_f32_16x16x32_bf16.
// A/B fragments loaded straight from global in MFMA layout (16 B/lane).
// MODE 0: A[row*ldA+k]  1: row=inv_win(row0+row)  2: conv gather (seg loop)
// EPI  0: bias->bf16  1: bias+GELU->bf16  2: bias+resb->fp32  3: scatter-resid RMW
template<int EPI, int MODE, int SEGP, int CSTR, int KPT>
__global__ __launch_bounds__(256, 4) void mgemm_kernel(const bf16* __restrict__ A,
        const bf16* __restrict__ BT, const float* __restrict__ bias,
        void* outp, int N, int row0, int ldA,
        const float* __restrict__ xres, const bf16* __restrict__ resb,
        const float* __restrict__ aab)
{
    int tid = threadIdx.x;
    int gm0 = blockIdx.x * 128;
    int n0  = blockIdx.y * 64;
    int lane = tid & 63, wv = tid >> 6;
    int quad = lane >> 4, l15 = lane & 15;

    f32x4 acc[2][4];
    #pragma unroll
    for (int i = 0; i < 2; i++)
        #pragma unroll
        for (int j = 0; j < 4; j++)
            acc[i][j] = (f32x4)0.f;

    const bf16* brow[4];
    #pragma unroll
    for (int j = 0; j < 4; j++)
        brow[j] = BT + (size_t)(n0 + j * 16 + l15) * KPT + quad * 8;

    if (MODE == 2){
        int py[2], px[2]; size_t pbase[2];
        #pragma unroll
        for (int i = 0; i < 2; i++){
            int m = gm0 + wv * 32 + i * 16 + l15;
            int bb = m >> 14, p = m & 16383;
            py[i] = p >> 7; px[i] = p & 127;
            pbase[i] = (size_t)bb << 14;
        }
        #pragma unroll
        for (int seg = 0; seg < 9; seg++){
            const int kh = seg / 3, kw = seg - kh * 3;
            const bf16* ap[2]; bool val[2];
            #pragma unroll
            for (int i = 0; i < 2; i++){
                int y = py[i] + kh - 1, xx = px[i] + kw - 1;
                val[i] = ((unsigned)y < 128u) && ((unsigned)xx < 128u);
                ap[i] = A + (pbase[i] + (size_t)(y * 128 + xx)) * CSTR + quad * 8;
            }
            constexpr int CIN = SEGP / 32;
            #pragma unroll
            for (int cc = 0; cc < CIN; cc++){
                short8v af[2], bfr[4];
                #pragma unroll
                for (int i = 0; i < 2; i++)
                    af[i] = val[i] ? ld8(ap[i] + cc * 32)
                                   : short8v{0,0,0,0,0,0,0,0};
                #pragma unroll
                for (int j = 0; j < 4; j++)
                    bfr[j] = ld8(brow[j] + seg * SEGP + cc * 32);
                #pragma unroll
                for (int i = 0; i < 2; i++)
                    #pragma unroll
                    for (int j = 0; j < 4; j++)
                        acc[i][j] = mfma16(af[i], bfr[j], acc[i][j]);
            }
        }
    } else {
        const bf16* arp[2];
        #pragma unroll
        for (int i = 0; i < 2; i++){
            int m = gm0 + wv * 32 + i * 16 + l15;
            if (MODE == 1) m = inv_win(row0 + m);
            arp[i] = A + (size_t)m * ldA + quad * 8;
        }
        constexpr int NCH = KPT / 32;
        #pragma unroll
        for (int kc = 0; kc < NCH; kc++){
            short8v af[2], bfr[4];
            #pragma unroll
            for (int i = 0; i < 2; i++) af[i] = ld8(arp[i] + kc * 32);
            #pragma unroll
            for (int j = 0; j < 4; j++) bfr[j] = ld8(brow[j] + kc * 32);
            #pragma unroll
            for (int i = 0; i < 2; i++)
                #pragma unroll
                for (int j = 0; j < 4; j++)
                    acc[i][j] = mfma16(af[i], bfr[j], acc[i][j]);
        }
    }

    // ---- epilogue: C/D layout col=lane&15, row=quad*4+reg ----
    #pragma unroll
    for (int i = 0; i < 2; i++){
        #pragma unroll
        for (int reg = 0; reg < 4; reg++){
            int gr = gm0 + wv * 32 + i * 16 + quad * 4 + reg;
            #pragma unroll
            for (int j = 0; j < 4; j++){
                int gc = n0 + j * 16 + l15;
                if (gc >= N) continue;
                float v = acc[i][j][reg] + bias[gc];
                if (EPI == 1) v = gelu_f(v);
                if (EPI == 0 || EPI == 1){
                    ((bf16*)outp)[(size_t)gr * N + gc] = f2b(v);
                } else if (EPI == 2){
                    size_t oi = (size_t)gr * N + gc;
                    ((float*)outp)[oi] = v + b2f(resb[oi]);
                } else {
                    int nr = inv_win(row0 + gr);
                    size_t oi = (size_t)nr * C_ + gc;
                    bf16* ob = (bf16*)outp;
                    v += xres[oi] + b2f(ob[oi]) * aab[(nr >> 14) * C_ + gc] * 0.01f;
                    ob[oi] = f2b(v);
                }
            }
        }
    }
}

// ================= MFMA windowed attention =================
#define KS_STR 36
#define VT_STR 260
#define P_STR  132
__global__ __launch_bounds__(256) void attn_kernel(const bf16* __restrict__ qkv,
        const bf16* __restrict__ biasT, bf16* __restrict__ attn_o)
{
    __shared__ short lds[256*KS_STR + 32*VT_STR + 64*P_STR];  // 51,968 B
    short* Ks = lds;
    short* Vt = lds + 256*KS_STR;
    bf16*  Pp = (bf16*)(lds + 256*KS_STR + 32*VT_STR);

    int tid = threadIdx.x;
    int win = blockIdx.x / NH_;
    int h   = blockIdx.x % NH_;
    const bf16* wbase = qkv + (size_t)win * NT_ * 540;

    {
        int t = tid;
        const bf16* row = wbase + (size_t)t * 540;
        const uint* kp = (const uint*)(row + 180 + h * HD_);
        const uint* vp = (const uint*)(row + 360 + h * HD_);
        uint* kd = (uint*)(Ks + t * KS_STR);
        #pragma unroll
        for (int i = 0; i < 15; i++) kd[i] = kp[i];
        kd[15] = 0; kd[16] = 0; kd[17] = 0;
        #pragma unroll
        for (int i = 0; i < 15; i++){
            uint w = vp[i];
            Vt[(2*i  ) * VT_STR + t] = (short)(w & 0xffff);
            Vt[(2*i+1) * VT_STR + t] = (short)(w >> 16);
        }
        Vt[30 * VT_STR + t] = 0;
        Vt[31 * VT_STR + t] = 0;
    }
    __syncthreads();

    int lane = tid & 63, wv = tid >> 6;
    int quad = lane >> 4, l15 = lane & 15;
    const bf16* qbase = wbase + h * HD_;
    const bf16* brow  = biasT + (size_t)h * 65536;

    for (int qb = 0; qb < 4; qb++){
        int qrow = qb * 64 + wv * 16 + l15;
        short8v af;
        {
            const uint* qp = (const uint*)(qbase + (size_t)qrow * 540 + quad * 8);
            union { uint u[4]; short8v v; } qa;
            qa.u[0] = qp[0]; qa.u[1] = qp[1]; qa.u[2] = qp[2]; qa.u[3] = qp[3];
            af = qa.v;
        }
        f32x4 Oacc[2];
        Oacc[0] = (f32x4)0.f; Oacc[1] = (f32x4)0.f;
        float lsum[4] = {0.f, 0.f, 0.f, 0.f};

        for (int kh = 0; kh < 2; kh++){
            f32x4 s[8];
            #pragma unroll
            for (int jt = 0; jt < 8; jt++) s[jt] = (f32x4)0.f;
            #pragma unroll
            for (int jt = 0; jt < 8; jt++){
                int tok = kh * 128 + jt * 16 + l15;
                const short* kp = Ks + tok * KS_STR + quad * 8;
                s[jt] = mfma16(af, cat44(*(const short4v*)kp, *(const short4v*)(kp + 4)), s[jt]);
            }
            float part[4] = {0.f, 0.f, 0.f, 0.f};
            #pragma unroll
            for (int jt = 0; jt < 8; jt++){
                int j = kh * 128 + jt * 16 + l15;
                #pragma unroll
                for (int reg = 0; reg < 4; reg++){
                    int i = qb * 64 + wv * 16 + quad * 4 + reg;
                    float v = s[jt][reg] * ATT_SCALE + b2f(brow[(size_t)i * 256 + j]);
                    float p = __expf(v);
                    part[reg] += p;
                    Pp[(wv * 16 + quad * 4 + reg) * P_STR + jt * 16 + l15] = f2b(p);
                }
            }
            #pragma unroll
            for (int m = 1; m < 16; m <<= 1){
                #pragma unroll
                for (int reg = 0; reg < 4; reg++)
                    part[reg] += __shfl_xor(part[reg], m);
            }
            #pragma unroll
            for (int reg = 0; reg < 4; reg++) lsum[reg] += part[reg];
            #pragma unroll
            for (int kc = 0; kc < 4; kc++){
                const short* pa_p = (const short*)Pp + (wv * 16 + l15) * P_STR
                                    + kc * 32 + quad * 8;
                short8v pa = cat44(*(const short4v*)pa_p, *(const short4v*)(pa_p + 4));
                #pragma unroll
                for (int jt2 = 0; jt2 < 2; jt2++){
                    const short* vb_p = Vt + (jt2 * 16 + l15) * VT_STR
                                        + kh * 128 + kc * 32 + quad * 8;
                    short8v vb = cat44(*(const short4v*)vb_p, *(const short4v*)(vb_p + 4));
                    Oacc[jt2] = mfma16(pa, vb, Oacc[jt2]);
                }
            }
        }
        #pragma unroll
        for (int jt2 = 0; jt2 < 2; jt2++){
            int d = jt2 * 16 + l15;
            if (d < HD_){
                #pragma unroll
                for (int reg = 0; reg < 4; reg++){
                    int qr = qb * 64 + wv * 16 + quad * 4 + reg;
                    attn_o[((size_t)win * NT_ + qr) * C_ + h * HD_ + d] =
                        f2b(Oacc[jt2][reg] / lsum[reg]);
                }
            }
        }
    }
}

extern "C" void kernel_launch(void* const* d_in, const int* in_sizes, int n_in,
                              void* d_out, int out_size, void* d_ws, size_t ws_size,
                              hipStream_t stream)
{
    const float* x      = (const float*)d_in[0];
    const int*   rpi    = (const int*)  d_in[1];
    const float* n1g    = (const float*)d_in[6];
    const float* n1b    = (const float*)d_in[7];
    const float* qkv_w  = (const float*)d_in[8];
    const float* qkv_b  = (const float*)d_in[9];
    const float* rpb    = (const float*)d_in[10];
    const float* proj_w = (const float*)d_in[11];
    const float* proj_b = (const float*)d_in[12];
    const float* c1w    = (const float*)d_in[13];
    const float* c1b    = (const float*)d_in[14];
    const float* c2w    = (const float*)d_in[15];
    const float* c2b    = (const float*)d_in[16];
    const float* ca1w   = (const float*)d_in[17];
    const float* ca1b   = (const float*)d_in[18];
    const float* ca2w   = (const float*)d_in[19];
    const float* ca2b   = (const float*)d_in[20];
    const float* n2g    = (const float*)d_in[21];
    const float* n2b    = (const float*)d_in[22];
    const float* fc1w   = (const float*)d_in[23];
    const float* fc1b   = (const float*)d_in[24];
    const float* fc2w   = (const float*)d_in[25];
    const float* fc2b   = (const float*)d_in[26];

    // ---- adaptive chunking: CH=2 needs ~96.5 MB, CH=4 needs ~72.9 MB ----
    size_t fixed = 23592960ull * 2 + 786432 + 1314816 + 5760;
    int CH = (ws_size >= (size_t)32768 * 1440 + fixed) ? 2 : 4;
    int CROWS = ROWS_ / CH;
    int CWIN  = CROWS / 256;
    size_t slab_sz = (size_t)CROWS * 1440;

    char* ws = (char*)d_ws;
    bf16*  slab   = (bf16*)(ws);
    bf16*  y1     = slab;
    bf16*  qkvb   = slab;
    bf16*  attn_o = (bf16*)(ws + (size_t)CROWS * 1080);
    bf16*  hbuf   = slab;
    bf16*  xn     = (bf16*)(ws + slab_sz);
    bf16*  resbuf = (bf16*)(ws + slab_sz + 23592960);
    bf16*  biasT  = (bf16*)(ws + slab_sz + 47185920);
    bf16*  qkvT   = (bf16*)((char*)biasT + 786432);
    bf16*  projT  = (bf16*)((char*)qkvT + 221184);
    bf16*  fc1T   = (bf16*)((char*)projT + 73728);
    bf16*  fc2T   = (bf16*)((char*)fc1T + 294912);
    bf16*  c1T    = (bf16*)((char*)fc2T + 282624);
    bf16*  c2T    = (bf16*)((char*)c1T + 221184);
    float* pooled = (float*)((char*)c2T + 221184);
    float* aab    = pooled + B_ * C_;

    hipMemsetAsync(pooled, 0, B_ * C_ * sizeof(float), stream);
    rpb_kernel<<<1536, 256, 0, stream>>>(rpb, rpi, biasT);
    twt_kernel<<<(576*192+255)/256, 256, 0, stream>>>(qkv_w, qkvT, 180, 540, 192, 576);
    twt_kernel<<<(192*192+255)/256, 256, 0, stream>>>(proj_w, projT, 180, 180, 192, 192);
    twt_kernel<<<(768*192+255)/256, 256, 0, stream>>>(fc1w, fc1T, 180, 720, 192, 768);
    twt_kernel<<<(192*736+255)/256, 256, 0, stream>>>(fc2w, fc2T, 720, 180, 736, 192);
    twc_kernel<<<(64*1728+255)/256, 256, 0, stream>>>(c1w, c1T, 180, 60, 192, 64);
    twc_kernel<<<(192*576+255)/256, 256, 0, stream>>>(c2w, c2T, 60, 180, 64, 192);

    ln_kernel<float><<<16384, 256, 0, stream>>>(x, n1g, n1b, xn);

    mgemm_kernel<1, 2, 192, 180, 1728><<<dim3(512, 1), 256, 0, stream>>>(
        xn, c1T, c1b, y1, 60, 0, 180, nullptr, nullptr, nullptr);
    mgemm_kernel<0, 2, 64, 60, 576><<<dim3(512, 3), 256, 0, stream>>>(
        y1, c2T, c2b, resbuf, 180, 0, 60, nullptr, nullptr, nullptr);
    pool_kernel<<<256, 192, 0, stream>>>(resbuf, pooled);
    ca_kernel<<<4, 192, 0, stream>>>(pooled, ca1w, ca1b, ca2w, ca2b, aab);

    for (int ch = 0; ch < CH; ch++){
        int row0 = ch * CROWS;
        mgemm_kernel<0, 1, 0, 0, 192><<<dim3(CROWS/128, 9), 256, 0, stream>>>(
            xn, qkvT, qkv_b, qkvb, 540, row0, 180, nullptr, nullptr, nullptr);
        attn_kernel<<<CWIN * NH_, 256, 0, stream>>>(qkvb, biasT, attn_o);
        mgemm_kernel<3, 0, 0, 0, 192><<<dim3(CROWS/128, 3), 256, 0, stream>>>(
            attn_o, projT, proj_b, resbuf, 180, row0, 180, x, nullptr, aab);
    }

    ln_kernel<bf16><<<16384, 256, 0, stream>>>(resbuf, n2g, n2b, xn);

    for (int ch = 0; ch < CH; ch++){
        size_t off = (size_t)ch * CROWS * C_;
        mgemm_kernel<1, 0, 0, 0, 192><<<dim3(CROWS/128, 12), 256, 0, stream>>>(
            xn + off, fc1T, fc1b, hbuf, 720, 0, 180, nullptr, nullptr, nullptr);
        mgemm_kernel<2, 0, 0, 0, 736><<<dim3(CROWS/128, 3), 256, 0, stream>>>(
            hbuf, fc2T, fc2b, (float*)d_out + off, 180, 0, 720,
            nullptr, resbuf + off, nullptr);
    }
}